// Round 8
// baseline (173.491 us; speedup 1.0000x reference)
//
#include <hip/hip_runtime.h>

#define NBINS    2048          // float bits >> 20 : 8 exp + 3 mantissa bits
#define THREADS  256
#define BLOCKS   1024          // 18 iters/thread exactly; ~4 blocks/CU resident
#define CNTSH    44            // count lives in bits [44,64) of packed u64
#define SAMPLE_SHIFT 3         // histogram 1/8 deterministic stride subsample

__device__ __forceinline__ void process_elem(
    float g, float p, bool sampled,
    unsigned int& posc, unsigned int& ignc, float& ps,
    unsigned long long* hist)
{
    // torch-style BCE with log clamp at -100:
    // loss = g*min(-log p,100) + (1-g)*min(-log(1-p),100)
    float nlp = fminf(-__logf(p), 100.0f);
    float nlq = fminf(-__logf(1.0f - p), 100.0f);
    float loss = fmaf(g, nlp - nlq, nlq);     // g*nlp + (1-g)*nlq

    bool isPos = (g >= 0.9f);
    bool isIgn = (g >= 0.8f) && !isPos;
    posc += isPos;
    ignc += isIgn;
    if (isPos) ps += loss;
    // histogram only sampled negatives (scaled x8 in finalize)
    if (sampled && g < 0.8f) {
        unsigned int b = 0;
        if (loss > 0.0f) {                     // guard loss==0 / -0.0
            b = __float_as_uint(loss) >> 20;
            if (b > NBINS - 1) b = NBINS - 1;
        }
        // fixed-point quantize (loss <= 100 fits u32); pack count|sum
        unsigned long long q =
            (unsigned long long)(unsigned int)(fmaf(loss, 1048576.0f, 0.5f));
        atomicAdd(&hist[b], (1ull << CNTSH) | q);
    }
}

__device__ __forceinline__ void process4(
    float4 g, float4 p, bool samp,
    unsigned int& posc, unsigned int& ignc, float& ps,
    unsigned long long* hist)
{
    process_elem(g.x, p.x, samp,  posc, ignc, ps, hist);
    process_elem(g.y, p.y, false, posc, ignc, ps, hist);
    process_elem(g.z, p.z, false, posc, ignc, ps, hist);
    process_elem(g.w, p.w, false, posc, ignc, ps, hist);
}

__global__ __launch_bounds__(THREADS) void pass1(
    const float* __restrict__ gt, const float* __restrict__ pred,
    unsigned int* __restrict__ counts, unsigned long long* __restrict__ sums,
    unsigned int* __restrict__ posIgn, double* __restrict__ psum,
    int n4, int nTail, long long tailBase)
{
    __shared__ unsigned long long hist[NBINS];
    for (int i = threadIdx.x; i < NBINS; i += THREADS) hist[i] = 0ull;
    __syncthreads();

    unsigned int posc = 0, ignc = 0;
    float ps = 0.0f;
    // stride even -> parity of index fixed; element 4i sampled iff i even
    const bool samp = ((threadIdx.x & 1) == 0);

    const float4* g4p = (const float4*)gt;
    const float4* p4p = (const float4*)pred;
    const int stride = gridDim.x * blockDim.x;
    int i = blockIdx.x * blockDim.x + threadIdx.x;
    // per-thread trip count (uniform: n4 divisible by stride for bench shape)
    int iters = (i < n4) ? ((n4 - 1 - i) / stride + 1) : 0;

    if (iters >= 2) {
        // 2-deep software pipeline: loads for iter t+2 issued before
        // processing iter t -> >=2 iterations of memory latency hidden.
        float4 gA = g4p[i];          float4 pA = p4p[i];
        float4 gB = g4p[i + stride]; float4 pB = p4p[i + stride];
        int idx = i;
        for (int t = 0; t < iters - 2; ++t) {
            float4 gC = g4p[idx + 2 * stride];
            float4 pC = p4p[idx + 2 * stride];
            process4(gA, pA, samp, posc, ignc, ps, hist);
            gA = gB; pA = pB; gB = gC; pB = pC;
            idx += stride;
        }
        process4(gA, pA, samp, posc, ignc, ps, hist);
        process4(gB, pB, samp, posc, ignc, ps, hist);
    } else if (iters == 1) {
        process4(g4p[i], p4p[i], samp, posc, ignc, ps, hist);
    }
    if (blockIdx.x == 0 && threadIdx.x < nTail) {
        long long e = tailBase + threadIdx.x;
        bool tsamp = ((e & 7) == 0);
        process_elem(gt[e], pred[e], tsamp, posc, ignc, ps, hist);
    }

    __syncthreads();
    // flush sparse per-block histogram: 1 u32 + 1 u64 atomic per hot bin
    for (int b = threadIdx.x; b < NBINS; b += THREADS) {
        unsigned long long v = hist[b];
        if (v) {
            atomicAdd(&counts[b], (unsigned int)(v >> CNTSH));
            atomicAdd(&sums[b],   v & ((1ull << CNTSH) - 1));
        }
    }

    // wave-64 reduce scalars, one atomic per wave
    double pd = (double)ps;
    for (int off = 32; off > 0; off >>= 1) {
        posc += __shfl_down(posc, off);
        ignc += __shfl_down(ignc, off);
        pd   += __shfl_down(pd, off);
    }
    if ((threadIdx.x & 63) == 0) {
        if (posc) atomicAdd(&posIgn[0], posc);
        if (ignc) atomicAdd(&posIgn[1], ignc);
        atomicAdd(psum, pd);
    }
}

__global__ __launch_bounds__(256) void finalize(
    const unsigned int* __restrict__ counts,
    const unsigned long long* __restrict__ sums,
    const unsigned int* __restrict__ posIgn, const double* __restrict__ psum,
    float* __restrict__ out, long long nTotal)
{
    __shared__ unsigned long long scnt[256];
    __shared__ double             ssum[256];
    __shared__ int                s_chunk;
    __shared__ double             s_topk;
    __shared__ double             s_allsum;

    const int t = threadIdx.x;
    const int BPT = NBINS / 256;          // 8 bins per thread
    const int base = t * BPT;
    const double INVFIX = 1.0 / 1048576.0;
    const double SCALE = (double)(1 << SAMPLE_SHIFT);   // 8.0

    unsigned long long c = 0; double s = 0.0;
    #pragma unroll
    for (int i = 0; i < BPT; ++i) {
        c += counts[base + i];
        s += (double)sums[base + i] * INVFIX;
    }
    scnt[t] = c; ssum[t] = s;
    if (t == 0) { s_chunk = -1; s_topk = 0.0; }
    __syncthreads();

    // inclusive suffix scan over 256 chunks (sample counts / sums)
    for (int off = 1; off < 256; off <<= 1) {
        unsigned long long cv = (t + off < 256) ? scnt[t + off] : 0ull;
        double             sv = (t + off < 256) ? ssum[t + off] : 0.0;
        __syncthreads();
        scnt[t] += cv; ssum[t] += sv;
        __syncthreads();
    }
    if (t == 0) s_allsum = ssum[0];
    __syncthreads();

    const unsigned int pos = posIgn[0];
    const unsigned int ign = posIgn[1];
    const unsigned long long neg =
        (unsigned long long)nTotal - pos - ign;        // EXACT negative count

    // k = floor(min(max(pos,1)*3.0, neg)) in f32, mirroring reference
    float kf = fminf(fmaxf((float)pos, 1.0f) * 3.0f, (float)neg);
    long long k = (long long)floorf(kf);
    unsigned long long ku = (unsigned long long)(k > 0 ? k : 0);

    unsigned long long Sincl = scnt[t];
    unsigned long long Sexcl = (t < 255) ? scnt[t + 1] : 0ull;
    double SexclSum          = (t < 255) ? ssum[t + 1] : 0.0;

    // compare in scaled (x8) space
    if (ku > 0 && (Sexcl << SAMPLE_SHIFT) < ku && (Sincl << SAMPLE_SHIFT) >= ku) {
        double topk = SCALE * SexclSum;
        double need = (double)ku - SCALE * (double)Sexcl;   // scaled rank deficit
        for (int i = BPT - 1; i >= 0 && need > 0.0; --i) {
            int b = base + i;
            unsigned long long cb = counts[b];
            if (!cb) continue;
            double sb = (double)sums[b] * INVFIX;           // sample sum in bin
            double nb = SCALE * (double)cb;                 // scaled bin count
            if (nb <= need) {
                topk += SCALE * sb;
                need -= nb;
            } else {
                // partial bin: uniform-within-bin model anchored at bin mean
                float lo = __uint_as_float((unsigned)b << 20);
                float hi = (b + 1 < NBINS) ? __uint_as_float((unsigned)(b + 1) << 20) : lo;
                double w = (double)hi - (double)lo;
                double mean = sb / (double)cb;
                topk += need * (mean + 0.5 * w * (1.0 - need / nb));
                need = 0.0;
            }
        }
        s_topk = topk;
        s_chunk = t;
    }
    __syncthreads();

    if (t == 0) {
        double topk;
        if (s_chunk >= 0)      topk = s_topk;
        else if (ku > 0)       topk = SCALE * s_allsum;  // k beyond scaled total
        else                   topk = 0.0;
        float denf = (float)pos + (float)k;
        denf += 1e-4f;
        double res = (3.0 * (*psum) + topk) / (double)denf;
        out[0] = (float)res;
    }
}

extern "C" void kernel_launch(void* const* d_in, const int* in_sizes, int n_in,
                              void* d_out, int out_size, void* d_ws, size_t ws_size,
                              hipStream_t stream) {
    const float* gt   = (const float*)d_in[0];
    const float* pred = (const float*)d_in[1];
    float* out = (float*)d_out;

    // ws: [0,8) f64 psum | [8,12) u32 pos | [12,16) u32 ign
    //     | [16, 16+NBINS*4) u32 counts | then NBINS*8 u64 sums
    double*             psum   = (double*)d_ws;
    unsigned int*       posIgn = (unsigned int*)((char*)d_ws + 8);
    unsigned int*       counts = (unsigned int*)((char*)d_ws + 16);
    unsigned long long* sums   = (unsigned long long*)((char*)d_ws + 16 + NBINS * sizeof(unsigned int));

    size_t zbytes = 16 + (size_t)NBINS * (sizeof(unsigned int) + sizeof(unsigned long long));
    hipMemsetAsync(d_ws, 0, zbytes, stream);

    long long n = (long long)in_sizes[0];
    int n4 = (int)(n >> 2);
    int nTail = (int)(n & 3);
    long long tailBase = (long long)n4 * 4;

    pass1<<<dim3(BLOCKS), dim3(THREADS), 0, stream>>>(
        gt, pred, counts, sums, posIgn, psum, n4, nTail, tailBase);
    finalize<<<dim3(1), dim3(256), 0, stream>>>(counts, sums, posIgn, psum, out, n);
}

// Round 9
// 129.715 us; speedup vs baseline: 1.3375x; 1.3375x over previous
//
#include <hip/hip_runtime.h>

#define NBINS    2048          // float bits >> 20 : 8 exp + 3 mantissa bits
#define REPL     4             // per-lane-group replicas (R2-proven codegen shape)
#define THREADS  512           // <-- the one change vs R2: 4 waves/SIMD at 2 blocks/CU
#define BLOCKS   512           // 2 blocks/CU x 256 CU; n4 = 18 * BLOCKS*THREADS exactly
#define FIXSH    20            // fixed-point scale 2^20 for loss sums
#define CNTSH    44            // count lives in bits [44,64)

__device__ __forceinline__ void process_elem(
    float g, float p,
    unsigned int& posc, float& ps,
    unsigned long long* hist, unsigned int repl)
{
    // torch-style BCE with log clamp at -100:
    // loss = g*min(-log p,100) + (1-g)*min(-log(1-p),100)
    float nlp = fminf(-__logf(p), 100.0f);
    float nlq = fminf(-__logf(1.0f - p), 100.0f);
    float loss = fmaf(g, nlp - nlq, nlq);     // g*nlp + (1-g)*nlq

    bool isPos = (g >= 0.9f);
    bool isNeg = (g < 0.8f);
    posc += isPos;
    if (isPos) ps += loss;
    if (isNeg) {
        unsigned int b = 0;
        if (loss > 0.0f) {                     // guard -0.0 / nonpositive
            b = __float_as_uint(loss) >> 20;
            if (b > NBINS - 1) b = NBINS - 1;
        }
        // fixed-point quantize (loss <= 100 -> fits u32); pack count|sum
        unsigned long long q =
            (unsigned long long)(unsigned int)(fmaf(loss, 1048576.0f, 0.5f));
        atomicAdd(&hist[(b << 2) | repl], (1ull << CNTSH) | q);
    }
}

__global__ __launch_bounds__(THREADS) void pass1(
    const float* __restrict__ gt, const float* __restrict__ pred,
    unsigned int* __restrict__ counts, unsigned long long* __restrict__ sums,
    unsigned int* __restrict__ posCnt, double* __restrict__ psum,
    int n4, int nTail, long long tailBase)
{
    __shared__ unsigned long long hist[NBINS * REPL];
    for (int i = threadIdx.x; i < NBINS * REPL; i += THREADS) hist[i] = 0ull;
    __syncthreads();

    unsigned int posc = 0;
    float ps = 0.0f;
    const unsigned int repl = threadIdx.x & (REPL - 1);

    const float4* g4p = (const float4*)gt;
    const float4* p4p = (const float4*)pred;
    const int stride = gridDim.x * blockDim.x;
    for (int i = blockIdx.x * blockDim.x + threadIdx.x; i < n4; i += stride) {
        float4 g4 = g4p[i];
        float4 p4 = p4p[i];
        process_elem(g4.x, p4.x, posc, ps, hist, repl);
        process_elem(g4.y, p4.y, posc, ps, hist, repl);
        process_elem(g4.z, p4.z, posc, ps, hist, repl);
        process_elem(g4.w, p4.w, posc, ps, hist, repl);
    }
    if (blockIdx.x == 0 && threadIdx.x < nTail) {
        long long i = tailBase + threadIdx.x;
        process_elem(gt[i], pred[i], posc, ps, hist, repl);
    }

    __syncthreads();
    // flush: fold 4 replicas (packed fields add safely: per-block sum < 2^44,
    // count < 2^20), then one u32 + one u64 global atomic per active bin
    for (int b = threadIdx.x; b < NBINS; b += THREADS) {
        unsigned long long v = hist[(b << 2) | 0] + hist[(b << 2) | 1]
                             + hist[(b << 2) | 2] + hist[(b << 2) | 3];
        if (v) {
            atomicAdd(&counts[b], (unsigned int)(v >> CNTSH));
            atomicAdd(&sums[b],   v & ((1ull << CNTSH) - 1));
        }
    }

    // wave-64 reduce scalars, one atomic per wave
    double pd = (double)ps;
    for (int off = 32; off > 0; off >>= 1) {
        posc += __shfl_down(posc, off);
        pd   += __shfl_down(pd, off);
    }
    if ((threadIdx.x & 63) == 0) {
        if (posc) atomicAdd(posCnt, posc);
        atomicAdd(psum, pd);
    }
}

__global__ __launch_bounds__(256) void finalize(
    const unsigned int* __restrict__ counts,
    const unsigned long long* __restrict__ sums,
    const unsigned int* __restrict__ posCnt, const double* __restrict__ psum,
    float* __restrict__ out)
{
    __shared__ unsigned long long scnt[256];
    __shared__ double             ssum[256];
    __shared__ int                s_chunk;
    __shared__ double             s_topk;

    const int t = threadIdx.x;
    const int BPT = NBINS / 256;          // 8 bins per thread
    const int base = t * BPT;
    const double INVFIX = 1.0 / 1048576.0;

    unsigned long long c = 0; double s = 0.0;
    #pragma unroll
    for (int i = 0; i < BPT; ++i) {
        c += counts[base + i];
        s += (double)sums[base + i] * INVFIX;
    }
    scnt[t] = c; ssum[t] = s;
    if (t == 0) { s_chunk = -1; s_topk = 0.0; }
    __syncthreads();

    // inclusive suffix scan over 256 chunks
    for (int off = 1; off < 256; off <<= 1) {
        unsigned long long cv = (t + off < 256) ? scnt[t + off] : 0ull;
        double             sv = (t + off < 256) ? ssum[t + off] : 0.0;
        __syncthreads();
        scnt[t] += cv; ssum[t] += sv;
        __syncthreads();
    }

    const unsigned int pos = posCnt[0];
    const unsigned long long total = scnt[0];   // exact negative count

    // k = floor(min(max(pos,1)*3.0, neg)) in f32, mirroring reference
    float kf = fminf(fmaxf((float)pos, 1.0f) * 3.0f, (float)total);
    long long k = (long long)floorf(kf);

    unsigned long long Sincl = scnt[t];
    unsigned long long Sexcl = (t < 255) ? scnt[t + 1] : 0ull;
    double SexclSum          = (t < 255) ? ssum[t + 1] : 0.0;

    if (k > 0 && Sexcl < (unsigned long long)k && Sincl >= (unsigned long long)k) {
        double topk = SexclSum;
        unsigned long long need = (unsigned long long)k - Sexcl;
        for (int i = BPT - 1; i >= 0 && need > 0; --i) {
            int b = base + i;
            unsigned long long cb = counts[b];
            if (!cb) continue;
            double sb = (double)sums[b] * INVFIX;
            if (cb <= need) {
                topk += sb;
                need -= cb;
            } else {
                // partial bin: uniform-within-bin model anchored at bin mean
                float lo = __uint_as_float((unsigned)b << 20);
                float hi = (b + 1 < NBINS) ? __uint_as_float((unsigned)(b + 1) << 20) : lo;
                double w = (double)hi - (double)lo;
                double n = (double)cb;
                double r = (double)need;
                double mean = sb / n;
                topk += r * (mean + 0.5 * w * (1.0 - r / n));
                need = 0;
            }
        }
        s_topk = topk;
        s_chunk = t;
    }
    __syncthreads();

    if (t == 0) {
        double topk = (s_chunk >= 0) ? s_topk : 0.0;
        float denf = (float)pos + (float)k;
        denf += 1e-4f;
        double res = (3.0 * (*psum) + topk) / (double)denf;
        out[0] = (float)res;
    }
}

extern "C" void kernel_launch(void* const* d_in, const int* in_sizes, int n_in,
                              void* d_out, int out_size, void* d_ws, size_t ws_size,
                              hipStream_t stream) {
    const float* gt   = (const float*)d_in[0];
    const float* pred = (const float*)d_in[1];
    float* out = (float*)d_out;

    // ws: [0,8) double psum | [8,12) u32 pos | pad | [16,16+8K) u32 counts
    //     | [16+8K, 16+8K+16K) u64 sums
    double*             psum   = (double*)d_ws;
    unsigned int*       posCnt = (unsigned int*)((char*)d_ws + 8);
    unsigned int*       counts = (unsigned int*)((char*)d_ws + 16);
    unsigned long long* sums   = (unsigned long long*)((char*)d_ws + 16 + NBINS * sizeof(unsigned int));

    size_t zbytes = 16 + (size_t)NBINS * (sizeof(unsigned int) + sizeof(unsigned long long));
    hipMemsetAsync(d_ws, 0, zbytes, stream);

    long long n = (long long)in_sizes[0];
    int n4 = (int)(n >> 2);
    int nTail = (int)(n & 3);
    long long tailBase = (long long)n4 * 4;

    pass1<<<dim3(BLOCKS), dim3(THREADS), 0, stream>>>(
        gt, pred, counts, sums, posCnt, psum, n4, nTail, tailBase);
    finalize<<<dim3(1), dim3(256), 0, stream>>>(counts, sums, posCnt, psum, out);
}

// Round 10
// 87.470 us; speedup vs baseline: 1.9834x; 1.4830x over previous
//
#include <hip/hip_runtime.h>

#define NBINS    2048          // float bits >> 20 : 8 exp + 3 mantissa bits
#define REPL     4             // per-lane-group replicas (R2-proven codegen shape)
#define THREADS  256
#define BLOCKS   512           // 2 blocks/CU, 64 KB LDS -> fat-codegen regime
#define CNTSH    44            // count lives in bits [44,64)

__device__ __forceinline__ void process_elem(
    float g, float p,
    unsigned int& posc, float& ps,
    unsigned long long* hist, unsigned int repl)
{
    // torch-style BCE with log clamp at -100:
    // loss = g*min(-log p,100) + (1-g)*min(-log(1-p),100)
    float nlp = fminf(-__logf(p), 100.0f);
    float nlq = fminf(-__logf(1.0f - p), 100.0f);
    float loss = fmaf(g, nlp - nlq, nlq);     // g*nlp + (1-g)*nlq

    bool isPos = (g >= 0.9f);
    bool isNeg = (g < 0.8f);
    posc += isPos;
    if (isPos) ps += loss;
    if (isNeg) {
        unsigned int b = 0;
        if (loss > 0.0f) {                     // guard -0.0 / nonpositive
            b = __float_as_uint(loss) >> 20;
            if (b > NBINS - 1) b = NBINS - 1;
        }
        // fixed-point quantize (loss <= 100 -> fits u32); pack count|sum
        unsigned long long q =
            (unsigned long long)(unsigned int)(fmaf(loss, 1048576.0f, 0.5f));
        atomicAdd(&hist[(b << 2) | repl], (1ull << CNTSH) | q);
    }
}

__device__ __forceinline__ void process4(
    float4 g, float4 p,
    unsigned int& posc, float& ps,
    unsigned long long* hist, unsigned int repl)
{
    process_elem(g.x, p.x, posc, ps, hist, repl);
    process_elem(g.y, p.y, posc, ps, hist, repl);
    process_elem(g.z, p.z, posc, ps, hist, repl);
    process_elem(g.w, p.w, posc, ps, hist, repl);
}

__global__ __launch_bounds__(THREADS) void pass1(
    const float* __restrict__ gt, const float* __restrict__ pred,
    unsigned int* __restrict__ counts, unsigned long long* __restrict__ sums,
    unsigned int* __restrict__ posCnt, double* __restrict__ psum,
    int n4, int nTail, long long tailBase)
{
    __shared__ unsigned long long hist[NBINS * REPL];
    for (int i = threadIdx.x; i < NBINS * REPL; i += THREADS) hist[i] = 0ull;
    __syncthreads();

    unsigned int posc = 0;
    float ps = 0.0f;
    const unsigned int repl = threadIdx.x & (REPL - 1);

    const float4* g4p = (const float4*)gt;
    const float4* p4p = (const float4*)pred;
    const int stride = gridDim.x * blockDim.x;
    int i = blockIdx.x * blockDim.x + threadIdx.x;

    // batches of 4 grid-stride iterations: all 8 float4 loads hoisted to the
    // top of the batch -> 4 iterations of memory latency exposed as ~1.
    // (n4 = 36*stride for the bench shape: 9 full batches, no remainder.)
    for (; i + 3 * stride < n4; i += 4 * stride) {
        float4 g0 = g4p[i];              float4 p0 = p4p[i];
        float4 g1 = g4p[i + stride];     float4 p1 = p4p[i + stride];
        float4 g2 = g4p[i + 2 * stride]; float4 p2 = p4p[i + 2 * stride];
        float4 g3 = g4p[i + 3 * stride]; float4 p3 = p4p[i + 3 * stride];

        process4(g0, p0, posc, ps, hist, repl);
        process4(g1, p1, posc, ps, hist, repl);
        process4(g2, p2, posc, ps, hist, repl);
        process4(g3, p3, posc, ps, hist, repl);
    }
    for (; i < n4; i += stride) {
        float4 g4 = g4p[i];
        float4 p4 = p4p[i];
        process4(g4, p4, posc, ps, hist, repl);
    }
    if (blockIdx.x == 0 && threadIdx.x < nTail) {
        long long e = tailBase + threadIdx.x;
        process_elem(gt[e], pred[e], posc, ps, hist, repl);
    }

    __syncthreads();
    // flush: fold 4 replicas (packed fields add safely: per-block sum < 2^44,
    // count < 2^20), then one u32 + one u64 global atomic per active bin
    for (int b = threadIdx.x; b < NBINS; b += THREADS) {
        unsigned long long v = hist[(b << 2) | 0] + hist[(b << 2) | 1]
                             + hist[(b << 2) | 2] + hist[(b << 2) | 3];
        if (v) {
            atomicAdd(&counts[b], (unsigned int)(v >> CNTSH));
            atomicAdd(&sums[b],   v & ((1ull << CNTSH) - 1));
        }
    }

    // wave-64 reduce scalars, one atomic per wave
    double pd = (double)ps;
    for (int off = 32; off > 0; off >>= 1) {
        posc += __shfl_down(posc, off);
        pd   += __shfl_down(pd, off);
    }
    if ((threadIdx.x & 63) == 0) {
        if (posc) atomicAdd(posCnt, posc);
        atomicAdd(psum, pd);
    }
}

__global__ __launch_bounds__(256) void finalize(
    const unsigned int* __restrict__ counts,
    const unsigned long long* __restrict__ sums,
    const unsigned int* __restrict__ posCnt, const double* __restrict__ psum,
    float* __restrict__ out)
{
    __shared__ unsigned long long scnt[256];
    __shared__ double             ssum[256];
    __shared__ int                s_chunk;
    __shared__ double             s_topk;

    const int t = threadIdx.x;
    const int BPT = NBINS / 256;          // 8 bins per thread
    const int base = t * BPT;
    const double INVFIX = 1.0 / 1048576.0;

    unsigned long long c = 0; double s = 0.0;
    #pragma unroll
    for (int i = 0; i < BPT; ++i) {
        c += counts[base + i];
        s += (double)sums[base + i] * INVFIX;
    }
    scnt[t] = c; ssum[t] = s;
    if (t == 0) { s_chunk = -1; s_topk = 0.0; }
    __syncthreads();

    // inclusive suffix scan over 256 chunks
    for (int off = 1; off < 256; off <<= 1) {
        unsigned long long cv = (t + off < 256) ? scnt[t + off] : 0ull;
        double             sv = (t + off < 256) ? ssum[t + off] : 0.0;
        __syncthreads();
        scnt[t] += cv; ssum[t] += sv;
        __syncthreads();
    }

    const unsigned int pos = posCnt[0];
    const unsigned long long total = scnt[0];   // exact negative count

    // k = floor(min(max(pos,1)*3.0, neg)) in f32, mirroring reference
    float kf = fminf(fmaxf((float)pos, 1.0f) * 3.0f, (float)total);
    long long k = (long long)floorf(kf);

    unsigned long long Sincl = scnt[t];
    unsigned long long Sexcl = (t < 255) ? scnt[t + 1] : 0ull;
    double SexclSum          = (t < 255) ? ssum[t + 1] : 0.0;

    if (k > 0 && Sexcl < (unsigned long long)k && Sincl >= (unsigned long long)k) {
        double topk = SexclSum;
        unsigned long long need = (unsigned long long)k - Sexcl;
        for (int i = BPT - 1; i >= 0 && need > 0; --i) {
            int b = base + i;
            unsigned long long cb = counts[b];
            if (!cb) continue;
            double sb = (double)sums[b] * INVFIX;
            if (cb <= need) {
                topk += sb;
                need -= cb;
            } else {
                // partial bin: uniform-within-bin model anchored at bin mean
                float lo = __uint_as_float((unsigned)b << 20);
                float hi = (b + 1 < NBINS) ? __uint_as_float((unsigned)(b + 1) << 20) : lo;
                double w = (double)hi - (double)lo;
                double n = (double)cb;
                double r = (double)need;
                double mean = sb / n;
                topk += r * (mean + 0.5 * w * (1.0 - r / n));
                need = 0;
            }
        }
        s_topk = topk;
        s_chunk = t;
    }
    __syncthreads();

    if (t == 0) {
        double topk = (s_chunk >= 0) ? s_topk : 0.0;
        float denf = (float)pos + (float)k;
        denf += 1e-4f;
        double res = (3.0 * (*psum) + topk) / (double)denf;
        out[0] = (float)res;
    }
}

extern "C" void kernel_launch(void* const* d_in, const int* in_sizes, int n_in,
                              void* d_out, int out_size, void* d_ws, size_t ws_size,
                              hipStream_t stream) {
    const float* gt   = (const float*)d_in[0];
    const float* pred = (const float*)d_in[1];
    float* out = (float*)d_out;

    // ws: [0,8) double psum | [8,12) u32 pos | pad | [16,16+8K) u32 counts
    //     | [16+8K, 16+8K+16K) u64 sums
    double*             psum   = (double*)d_ws;
    unsigned int*       posCnt = (unsigned int*)((char*)d_ws + 8);
    unsigned int*       counts = (unsigned int*)((char*)d_ws + 16);
    unsigned long long* sums   = (unsigned long long*)((char*)d_ws + 16 + NBINS * sizeof(unsigned int));

    size_t zbytes = 16 + (size_t)NBINS * (sizeof(unsigned int) + sizeof(unsigned long long));
    hipMemsetAsync(d_ws, 0, zbytes, stream);

    long long n = (long long)in_sizes[0];
    int n4 = (int)(n >> 2);
    int nTail = (int)(n & 3);
    long long tailBase = (long long)n4 * 4;

    pass1<<<dim3(BLOCKS), dim3(THREADS), 0, stream>>>(
        gt, pred, counts, sums, posCnt, psum, n4, nTail, tailBase);
    finalize<<<dim3(1), dim3(256), 0, stream>>>(counts, sums, posCnt, psum, out);
}